// Round 17
// baseline (47.497 us; speedup 1.0000x reference)
//
#include <hip/hip_runtime.h>

#define BATCH 4
#define QDIM 1024
#define KDIM 1024
#define EDIM 512
#define H 32
#define VDIM 256
#define QT 16

#define TWO_LOG2E 2.8853900817779268f
#define LOG2E 1.4426950408889634f

typedef __attribute__((ext_vector_type(8))) short short8;
typedef __attribute__((ext_vector_type(4))) float f32x4;
typedef __attribute__((ext_vector_type(2))) float f32x2;

typedef __attribute__((address_space(3))) void lds_void_t;
typedef __attribute__((address_space(1))) const void gbl_cvoid_t;

// async global->LDS, 16B per lane. LDS dest = wave-uniform base + lane*16.
static __device__ __forceinline__ void gll16(const void* g, void* l) {
    __builtin_amdgcn_global_load_lds((gbl_cvoid_t*)g, (lds_void_t*)l, 16, 0, 0);
}

static __device__ __forceinline__ unsigned short f32_to_bf16(float f) {
    unsigned int bits = __float_as_uint(f);
    return (unsigned short)((bits + 0x7FFFu + ((bits >> 16) & 1u)) >> 16);
}

static __device__ __forceinline__ unsigned int pack_bf16(float a, float b) {
    unsigned int ua = __float_as_uint(a) + 0x8000u;
    unsigned int ub = __float_as_uint(b) + 0x8000u;
    return __builtin_amdgcn_perm(ub, ua, 0x07060302u);  // lo=a.hi16, hi=b.hi16
}

// ---------------------------------------------------------------------------
// Prep kernel (exact round-15 structure). Blocks 0..255: MFMA projection with
// inline W transpose (W fragments consumed from LDS — global fragment reads
// are a 16-line scatter, round-16 lesson). Blocks 256..511: V -> bf16
// fragment-major vt[b][w][kc][lane*16B], XCD-affine.
// ---------------------------------------------------------------------------
__global__ __launch_bounds__(256) void prep_kernel(
    const float* __restrict__ qin, const float* __restrict__ kin,
    const float* __restrict__ Wqm, const float* __restrict__ Wkm,
    const float* __restrict__ values,
    float* __restrict__ qp, float* __restrict__ kp,
    unsigned short* __restrict__ vt)
{
    __shared__ float t[64][65];
    __shared__ f32x4 lacc[2][64][2];
    __shared__ unsigned short wlds[32][520];     // Wt[h][e], padded rows
    const int tid = (int)threadIdx.x;
    const int bid = (int)blockIdx.x;

    if (bid < 256) {
        const int wave = tid >> 6, lane = tid & 63;
        const int tile = wave >> 1;                  // 0,1
        const int khalf = wave & 1;                  // 0,1
        const int grow = bid * 32 + tile * 16;       // 0..8191 (16-row tile)
        const bool is_k = grow >= 4096;
        const float* X = is_k ? kin : qin;
        const float* W = is_k ? Wkm : Wqm;
        const int row0 = is_k ? grow - 4096 : grow;
        const int arow = lane & 15, aq = lane >> 4;

        // inline W transpose: W[e][h] fp32 -> wlds[h][e] bf16 (coalesced read)
        for (int i = 0; i < 64; ++i) {
            const int idx = i * 256 + tid;
            wlds[idx & 31][idx >> 5] = f32_to_bf16(W[idx]);
        }
        __syncthreads();

        const float* xrow = X + (size_t)(row0 + arow) * EDIM + khalf * 256 + aq * 8;
        const unsigned short* wt0 = &wlds[arow][khalf * 256 + aq * 8];
        const unsigned short* wt1 = &wlds[arow + 16][khalf * 256 + aq * 8];

        f32x4 acc0 = {0.f, 0.f, 0.f, 0.f};
        f32x4 acc1 = {0.f, 0.f, 0.f, 0.f};
        #pragma unroll
        for (int s = 0; s < 8; ++s) {
            float4 xa = *reinterpret_cast<const float4*>(xrow + s * 32);
            float4 xb = *reinterpret_cast<const float4*>(xrow + s * 32 + 4);
            unsigned int p0 = pack_bf16(xa.x, xa.y);
            unsigned int p1 = pack_bf16(xa.z, xa.w);
            unsigned int p2 = pack_bf16(xb.x, xb.y);
            unsigned int p3 = pack_bf16(xb.z, xb.w);
            uint4 au = make_uint4(p0, p1, p2, p3);
            short8 af = *reinterpret_cast<const short8*>(&au);
            short8 b0 = *reinterpret_cast<const short8*>(wt0 + s * 32);
            short8 b1 = *reinterpret_cast<const short8*>(wt1 + s * 32);
            acc0 = __builtin_amdgcn_mfma_f32_16x16x32_bf16(af, b0, acc0, 0, 0, 0);
            acc1 = __builtin_amdgcn_mfma_f32_16x16x32_bf16(af, b1, acc1, 0, 0, 0);
        }
        if (khalf == 1) {
            lacc[tile][lane][0] = acc0;
            lacc[tile][lane][1] = acc1;
        }
        __syncthreads();
        if (khalf == 0) {
            f32x4 o0 = lacc[tile][lane][0];
            f32x4 o1 = lacc[tile][lane][1];
            acc0 += o0; acc1 += o1;
            if (is_k) {
                #pragma unroll
                for (int r = 0; r < 4; ++r) {
                    const int row = aq * 4 + r;      // C/D: row=(lane>>4)*4+reg
                    float* orow = kp + (size_t)(row0 + row) * H;
                    orow[arow]      = __builtin_amdgcn_exp2f(acc0[r] * TWO_LOG2E);
                    orow[arow + 16] = __builtin_amdgcn_exp2f(acc1[r] * TWO_LOG2E);
                }
            } else {
                float* tbase = qp + (size_t)(row0 >> 4) * 512;   // [h][16]
                #pragma unroll
                for (int r = 0; r < 4; ++r) {
                    const int row = aq * 4 + r;
                    tbase[arow * 16 + row]        = __builtin_amdgcn_exp2f(acc0[r] * TWO_LOG2E);
                    tbase[(arow + 16) * 16 + row] = __builtin_amdgcn_exp2f(acc1[r] * TWO_LOG2E);
                }
            }
        }
    } else {
        // XCD-affinity decode: pid%8 -> xcd; batch b = xcd>>1.
        const int pid  = bid - 256;
        const int xcd  = pid & 7, slot = pid >> 3;
        const int b    = xcd >> 1;
        const int tnum = slot * 2 + (xcd & 1);       // 0..63
        const int kt = tnum & 15, ct = tnum >> 4;
        const int k0 = kt * 64, c0 = ct * 64;
        const int col4 = (tid & 15) * 4;
        const int krow = tid >> 4;

        #pragma unroll
        for (int i = 0; i < 4; ++i) {
            const int kk = i * 16 + krow;
            float4 v = *reinterpret_cast<const float4*>(
                values + ((size_t)(b * KDIM + k0 + kk) * VDIM + c0 + col4));
            t[kk][col4 + 0] = v.x; t[kk][col4 + 1] = v.y;
            t[kk][col4 + 2] = v.z; t[kk][col4 + 3] = v.w;
        }
        __syncthreads();

        const int col = tid >> 2;                    // 0..63 within tile
        const int ks  = (tid & 3) * 16;
        unsigned int pk[8];
        #pragma unroll
        for (int j = 0; j < 8; ++j) {
            unsigned int lo = f32_to_bf16(t[ks + 2 * j][col]);
            unsigned int hi = f32_to_bf16(t[ks + 2 * j + 1][col]);
            pk[j] = lo | (hi << 16);
        }
        // fragment-major store: uint4 idx = ((b*16+w)*32+kc)*64 + aq*16 + arow
        const int colg = c0 + col;
        const int w_ = colg >> 4, arow_ = colg & 15;
        const int kA = k0 + ks, kB = kA + 8;
        uint4* vt4 = reinterpret_cast<uint4*>(vt);
        const size_t idxA = ((size_t)(b * 16 + w_) * 32 + (kA >> 5)) * 64
                            + ((kA >> 3) & 3) * 16 + arow_;
        const size_t idxB = ((size_t)(b * 16 + w_) * 32 + (kB >> 5)) * 64
                            + ((kB >> 3) & 3) * 16 + arow_;
        vt4[idxA] = make_uint4(pk[0], pk[1], pk[2], pk[3]);
        vt4[idxB] = make_uint4(pk[4], pk[5], pk[6], pk[7]);
    }
}

// ---------------------------------------------------------------------------
// Fused scores -> softmax -> MFMA PV. QT=16 q rows per block.
// grid = 256 x 1024 threads, now 2 blocks/CU (LDS 64.06KB): V ring shrunk to
// 2 slabs, prefetch distance 1. Cross-block overlap hides barrier stalls.
// ---------------------------------------------------------------------------
__global__ __launch_bounds__(1024, 8) void attn_fused(
    const float* __restrict__ qp, const float* __restrict__ kp,
    const unsigned short* __restrict__ vt, const float* __restrict__ wv,
    float* __restrict__ out)
{
    __shared__ __align__(16) unsigned char a_lds[32 * 1024];
    __shared__ __align__(16) unsigned char slab[16 * 2 * 1024];  // 16 waves x 2 x 1KB
    __shared__ float inv_lds[QT];

    const int tid = (int)threadIdx.x;
    const int pid = (int)blockIdx.x;
    const int xcd = pid & 7, slot = pid >> 3;
    const int b   = xcd >> 1;                        // batch 0..3
    const int tnum = slot * 2 + (xcd & 1);           // q-tile 0..63
    const int q0  = tnum * QT;

    float sumwv = 0.f;
    #pragma unroll
    for (int h = 0; h < H; ++h) sumwv += wv[h];
    const float c0s = sumwv * LOG2E;
    const float c1s = 2.0f * LOG2E;

    // ---- phase 1: one k-row per thread, 8 qr-pairs, packed f32 math ----
    {
        const int kk   = tid;
        const int base = (kk >> 5) * 1024 + (kk & 31) * 2;
        float kreg[H];
        const float* krow = kp + (size_t)(b * KDIM + kk) * H;
        #pragma unroll
        for (int i = 0; i < H / 4; ++i) {
            float4 v = *reinterpret_cast<const float4*>(krow + i * 4);
            kreg[i * 4 + 0] = v.x; kreg[i * 4 + 1] = v.y;
            kreg[i * 4 + 2] = v.z; kreg[i * 4 + 3] = v.w;
        }
        const float* eqt = qp + (size_t)((b << 6) | tnum) * 512;

        for (int p = 0; p < 8; ++p) {
            f32x2 s2e = {0.f, 0.f}, s2o = {0.f, 0.f};
            #pragma unroll
            for (int g = 0; g < 8; ++g) {
                const int h = g * 4;
                f32x2 e0 = *reinterpret_cast<const f32x2*>(eqt + (h + 0) * 16 + 2 * p);
                f32x2 e1 = *reinterpret_cast<const f32x2*>(eqt + (h + 1) * 16 + 2 * p);
                f32x2 e2 = *reinterpret_cast<const f32x2*>(eqt + (h + 2) * 16 + 2 * p);
                f32x2 e3 = *reinterpret_cast<const f32x2*>(eqt + (h + 3) * 16 + 2 * p);
                const f32x2 one = {1.f, 1.f};
                f32x2 U0 = e0 * (f32x2){kreg[h + 0], kreg[h + 0]} + one;
                f32x2 U1 = e1 * (f32x2){kreg[h + 1], kreg[h + 1]} + one;
                f32x2 U2 = e2 * (f32x2){kreg[h + 2], kreg[h + 2]} + one;
                f32x2 U3 = e3 * (f32x2){kreg[h + 3], kreg[h + 3]} + one;
                f32x2 n01 = U1 * (f32x2){wv[h + 0], wv[h + 0]}
                          + U0 * (f32x2){wv[h + 1], wv[h + 1]};
                f32x2 n23 = U3 * (f32x2){wv[h + 2], wv[h + 2]}
                          + U2 * (f32x2){wv[h + 3], wv[h + 3]};
                f32x2 d01 = U0 * U1;
                f32x2 d23 = U2 * U3;
                f32x2 n = n01 * d23 + n23 * d01;
                f32x2 d = d01 * d23;
                f32x2 r;
                r.x = __builtin_amdgcn_rcpf(d.x);
                r.y = __builtin_amdgcn_rcpf(d.y);
                if (g & 1) s2o += n * r; else s2e += n * r;
            }
            f32x2 s2 = s2e + s2o;
            float wgtA = __builtin_amdgcn_exp2f(fmaf(-c1s, s2.x, c0s));
            float wgtB = __builtin_amdgcn_exp2f(fmaf(-c1s, s2.y, c0s));
            const int qrA = 2 * p, qrB = 2 * p + 1;
            const int addrA = (base + qrA * 64) ^ ((qrA & 7) << 4);
            const int addrB = (base + qrB * 64) ^ ((qrB & 7) << 4);
            *reinterpret_cast<unsigned short*>(a_lds + addrA) = f32_to_bf16(wgtA);
            *reinterpret_cast<unsigned short*>(a_lds + addrB) = f32_to_bf16(wgtB);
        }
    }
    __syncthreads();

    // ---- phase 2: softmax denominator, one wave per q row ----
    {
        const int row = tid >> 6;                 // 0..15
        const int c   = tid & 63;
        float s = 0.f;
        #pragma unroll
        for (int j = 0; j < 16; ++j) {
            const int k = c + j * 64;
            const int addr = ((k >> 5) * 1024 + row * 64 + (k & 31) * 2)
                             ^ ((row & 7) << 4);
            unsigned int u = *reinterpret_cast<const unsigned short*>(a_lds + addr);
            s += __uint_as_float(u << 16);
        }
        #pragma unroll
        for (int m = 32; m > 0; m >>= 1) s += __shfl_xor(s, m, 64);
        if (c == 0) inv_lds[row] = 1.0f / s;
    }
    __syncthreads();

    // ---- phase 3: MFMA PV, per-wave async V ring (2 slabs, distance 1) ----
    const int w    = tid >> 6;                    // 0..15
    const int lane = tid & 63;
    const int colb = w * 16;
    const int arow = lane & 15;                   // A row / B col / D col
    const int aq   = lane >> 4;                   // k-quad
    f32x4 acc = {0.f, 0.f, 0.f, 0.f};
    {
        const char* gsrc = reinterpret_cast<const char*>(vt)
                         + ((size_t)(b * 16 + w) * 32) * 1024 + lane * 16;
        char* lbase = reinterpret_cast<char*>(slab) + w * 2048;  // 2 x 1KB ring

        gll16(gsrc, lbase);                        // prefetch slab 0

        #pragma unroll 4
        for (int kc = 0; kc < 31; ++kc) {
            gll16(gsrc + (kc + 1) * 1024, lbase + ((kc + 1) & 1) * 1024);
            asm volatile("s_waitcnt vmcnt(1)" ::: "memory");
            const int aaddr = (kc * 1024 + arow * 64 + aq * 16) ^ ((arow & 7) << 4);
            short8 af = *reinterpret_cast<const short8*>(a_lds + aaddr);
            short8 bv = *reinterpret_cast<const short8*>(lbase + (kc & 1) * 1024 + lane * 16);
            acc = __builtin_amdgcn_mfma_f32_16x16x32_bf16(af, bv, acc, 0, 0, 0);
        }
        {   // tail kc = 31
            asm volatile("s_waitcnt vmcnt(0)" ::: "memory");
            const int aaddr = (31 * 1024 + arow * 64 + aq * 16) ^ ((arow & 7) << 4);
            short8 af = *reinterpret_cast<const short8*>(a_lds + aaddr);
            short8 bv = *reinterpret_cast<const short8*>(lbase + (31 & 1) * 1024 + lane * 16);
            acc = __builtin_amdgcn_mfma_f32_16x16x32_bf16(af, bv, acc, 0, 0, 0);
        }
    }

    // ---- epilogue: stage tile in LDS, then ONE coalesced float4 per thread ----
    __syncthreads();                               // all a_lds MFMA reads done
    {
        float* otile = reinterpret_cast<float*>(a_lds);   // [16][264] padded
        #pragma unroll
        for (int r = 0; r < 4; ++r) {
            const int row = aq * 4 + r;            // C/D: row=(lane>>4)*4+reg
            otile[row * 264 + colb + arow] = acc[r] * inv_lds[row];
        }
    }
    __syncthreads();
    {
        const float* otile = reinterpret_cast<const float*>(a_lds);
        const int row = tid >> 6;                  // 0..15
        const int c4  = (tid & 63) * 4;            // 0..252
        f32x4 v = *reinterpret_cast<const f32x4*>(&otile[row * 264 + c4]);
        *reinterpret_cast<f32x4*>(out + (size_t)(b * QDIM + q0 + row) * VDIM + c4) = v;
    }
}

extern "C" void kernel_launch(void* const* d_in, const int* in_sizes, int n_in,
                              void* d_out, int out_size, void* d_ws, size_t ws_size,
                              hipStream_t stream) {
    const float* queries = (const float*)d_in[0];
    const float* keys    = (const float*)d_in[1];
    const float* values  = (const float*)d_in[2];
    const float* Wq      = (const float*)d_in[3];
    const float* Wk      = (const float*)d_in[4];
    const float* wv      = (const float*)d_in[5];
    float* out = (float*)d_out;

    float* qp = (float*)d_ws;                            // Eq, [256 tiles][32 h][16 r]
    float* kp = qp + (size_t)BATCH * QDIM * H;           // Ek, [4096][32]
    unsigned short* vt = (unsigned short*)(kp + (size_t)BATCH * KDIM * H); // vt, 2MB

    hipLaunchKernelGGL(prep_kernel, dim3(512), dim3(256), 0, stream,
                       queries, keys, Wq, Wk, values, qp, kp, vt);
    hipLaunchKernelGGL(attn_fused, dim3(BATCH * (QDIM / QT)), dim3(1024), 0, stream,
                       qp, kp, vt, wv, out);
}

// Round 18
// 35.804 us; speedup vs baseline: 1.3266x; 1.3266x over previous
//
#include <hip/hip_runtime.h>

#define BATCH 4
#define QDIM 1024
#define KDIM 1024
#define EDIM 512
#define H 32
#define VDIM 256
#define QT 16

#define TWO_LOG2E 2.8853900817779268f
#define LOG2E 1.4426950408889634f

typedef __attribute__((ext_vector_type(8))) short short8;
typedef __attribute__((ext_vector_type(4))) float f32x4;
typedef __attribute__((ext_vector_type(2))) float f32x2;

typedef __attribute__((address_space(3))) void lds_void_t;
typedef __attribute__((address_space(1))) const void gbl_cvoid_t;

// async global->LDS, 16B per lane. LDS dest = wave-uniform base + lane*16.
static __device__ __forceinline__ void gll16(const void* g, void* l) {
    __builtin_amdgcn_global_load_lds((gbl_cvoid_t*)g, (lds_void_t*)l, 16, 0, 0);
}

static __device__ __forceinline__ unsigned short f32_to_bf16(float f) {
    unsigned int bits = __float_as_uint(f);
    return (unsigned short)((bits + 0x7FFFu + ((bits >> 16) & 1u)) >> 16);
}

static __device__ __forceinline__ unsigned int pack_bf16(float a, float b) {
    unsigned int ua = __float_as_uint(a) + 0x8000u;
    unsigned int ub = __float_as_uint(b) + 0x8000u;
    return __builtin_amdgcn_perm(ub, ua, 0x07060302u);  // lo=a.hi16, hi=b.hi16
}

// ---------------------------------------------------------------------------
// Kernel 0: Wt[h][e] = bf16(W[e][h]). 128 blocks x 256 thr, 1 elem/thread.
// ---------------------------------------------------------------------------
__global__ __launch_bounds__(256) void wprep_kernel(
    const float* __restrict__ Wqm, const float* __restrict__ Wkm,
    unsigned short* __restrict__ wtq, unsigned short* __restrict__ wtk)
{
    const bool is_k = blockIdx.x >= 64;
    const float* W = is_k ? Wkm : Wqm;
    unsigned short* Wt = is_k ? wtk : wtq;
    const int idx = ((int)blockIdx.x & 63) * 256 + (int)threadIdx.x;
    const int e = idx >> 5, c = idx & 31;            // coalesced read
    Wt[(size_t)c * EDIM + e] = f32_to_bf16(W[idx]);
}

// ---------------------------------------------------------------------------
// Prep kernel (r15 structure). Blocks 0..255: MFMA projection; Wt staged into
// padded LDS via 8 coalesced uint4 copies/thread (fragments consumed from LDS
// — global fragment reads are a 16-line scatter, round-16 lesson).
// Blocks 256..511: V -> bf16 fragment-major vt[b][w][kc][lane*16B], XCD-affine.
// ---------------------------------------------------------------------------
__global__ __launch_bounds__(256) void prep_kernel(
    const float* __restrict__ qin, const float* __restrict__ kin,
    const unsigned short* __restrict__ wtq, const unsigned short* __restrict__ wtk,
    const float* __restrict__ values,
    float* __restrict__ qp, float* __restrict__ kp,
    unsigned short* __restrict__ vt)
{
    __shared__ float t[64][65];
    __shared__ f32x4 lacc[2][64][2];
    __shared__ unsigned short wlds[32][520];     // Wt[h][e], padded rows (1040B, 16B-aligned)
    const int tid = (int)threadIdx.x;
    const int bid = (int)blockIdx.x;

    if (bid < 256) {
        const int wave = tid >> 6, lane = tid & 63;
        const int tile = wave >> 1;                  // 0,1
        const int khalf = wave & 1;                  // 0,1
        const int grow = bid * 32 + tile * 16;       // 0..8191 (16-row tile)
        const bool is_k = grow >= 4096;
        const float* X = is_k ? kin : qin;
        const unsigned short* Wt = is_k ? wtk : wtq;
        const int row0 = is_k ? grow - 4096 : grow;
        const int arow = lane & 15, aq = lane >> 4;

        // stage Wt [32][512] bf16 -> padded wlds: 8 x (uint4 load + b128 store)
        {
            const uint4* wt4 = reinterpret_cast<const uint4*>(Wt);
            #pragma unroll
            for (int i = 0; i < 8; ++i) {
                const int idx = i * 256 + tid;       // 0..2047 uint4 slots
                const int hrow = idx >> 6;           // 64 uint4 per 512-elem row
                const int e8   = (idx & 63) * 8;
                *reinterpret_cast<uint4*>(&wlds[hrow][e8]) = wt4[idx];
            }
        }
        __syncthreads();

        const float* xrow = X + (size_t)(row0 + arow) * EDIM + khalf * 256 + aq * 8;
        const unsigned short* wt0 = &wlds[arow][khalf * 256 + aq * 8];
        const unsigned short* wt1 = &wlds[arow + 16][khalf * 256 + aq * 8];

        f32x4 acc0 = {0.f, 0.f, 0.f, 0.f};
        f32x4 acc1 = {0.f, 0.f, 0.f, 0.f};
        #pragma unroll
        for (int s = 0; s < 8; ++s) {
            float4 xa = *reinterpret_cast<const float4*>(xrow + s * 32);
            float4 xb = *reinterpret_cast<const float4*>(xrow + s * 32 + 4);
            unsigned int p0 = pack_bf16(xa.x, xa.y);
            unsigned int p1 = pack_bf16(xa.z, xa.w);
            unsigned int p2 = pack_bf16(xb.x, xb.y);
            unsigned int p3 = pack_bf16(xb.z, xb.w);
            uint4 au = make_uint4(p0, p1, p2, p3);
            short8 af = *reinterpret_cast<const short8*>(&au);
            short8 b0 = *reinterpret_cast<const short8*>(wt0 + s * 32);
            short8 b1 = *reinterpret_cast<const short8*>(wt1 + s * 32);
            acc0 = __builtin_amdgcn_mfma_f32_16x16x32_bf16(af, b0, acc0, 0, 0, 0);
            acc1 = __builtin_amdgcn_mfma_f32_16x16x32_bf16(af, b1, acc1, 0, 0, 0);
        }
        if (khalf == 1) {
            lacc[tile][lane][0] = acc0;
            lacc[tile][lane][1] = acc1;
        }
        __syncthreads();
        if (khalf == 0) {
            f32x4 o0 = lacc[tile][lane][0];
            f32x4 o1 = lacc[tile][lane][1];
            acc0 += o0; acc1 += o1;
            if (is_k) {
                #pragma unroll
                for (int r = 0; r < 4; ++r) {
                    const int row = aq * 4 + r;      // C/D: row=(lane>>4)*4+reg
                    float* orow = kp + (size_t)(row0 + row) * H;
                    orow[arow]      = __builtin_amdgcn_exp2f(acc0[r] * TWO_LOG2E);
                    orow[arow + 16] = __builtin_amdgcn_exp2f(acc1[r] * TWO_LOG2E);
                }
            } else {
                float* tbase = qp + (size_t)(row0 >> 4) * 512;   // [h][16]
                #pragma unroll
                for (int r = 0; r < 4; ++r) {
                    const int row = aq * 4 + r;
                    tbase[arow * 16 + row]        = __builtin_amdgcn_exp2f(acc0[r] * TWO_LOG2E);
                    tbase[(arow + 16) * 16 + row] = __builtin_amdgcn_exp2f(acc1[r] * TWO_LOG2E);
                }
            }
        }
    } else {
        // XCD-affinity decode: pid%8 -> xcd; batch b = xcd>>1.
        const int pid  = bid - 256;
        const int xcd  = pid & 7, slot = pid >> 3;
        const int b    = xcd >> 1;
        const int tnum = slot * 2 + (xcd & 1);       // 0..63
        const int kt = tnum & 15, ct = tnum >> 4;
        const int k0 = kt * 64, c0 = ct * 64;
        const int col4 = (tid & 15) * 4;
        const int krow = tid >> 4;

        #pragma unroll
        for (int i = 0; i < 4; ++i) {
            const int kk = i * 16 + krow;
            float4 v = *reinterpret_cast<const float4*>(
                values + ((size_t)(b * KDIM + k0 + kk) * VDIM + c0 + col4));
            t[kk][col4 + 0] = v.x; t[kk][col4 + 1] = v.y;
            t[kk][col4 + 2] = v.z; t[kk][col4 + 3] = v.w;
        }
        __syncthreads();

        const int col = tid >> 2;                    // 0..63 within tile
        const int ks  = (tid & 3) * 16;
        unsigned int pk[8];
        #pragma unroll
        for (int j = 0; j < 8; ++j) {
            unsigned int lo = f32_to_bf16(t[ks + 2 * j][col]);
            unsigned int hi = f32_to_bf16(t[ks + 2 * j + 1][col]);
            pk[j] = lo | (hi << 16);
        }
        // fragment-major store: uint4 idx = ((b*16+w)*32+kc)*64 + aq*16 + arow
        const int colg = c0 + col;
        const int w_ = colg >> 4, arow_ = colg & 15;
        const int kA = k0 + ks, kB = kA + 8;
        uint4* vt4 = reinterpret_cast<uint4*>(vt);
        const size_t idxA = ((size_t)(b * 16 + w_) * 32 + (kA >> 5)) * 64
                            + ((kA >> 3) & 3) * 16 + arow_;
        const size_t idxB = ((size_t)(b * 16 + w_) * 32 + (kB >> 5)) * 64
                            + ((kB >> 3) & 3) * 16 + arow_;
        vt4[idxA] = make_uint4(pk[0], pk[1], pk[2], pk[3]);
        vt4[idxB] = make_uint4(pk[4], pk[5], pk[6], pk[7]);
    }
}

// ---------------------------------------------------------------------------
// Fused scores -> softmax -> MFMA PV. QT=16 q rows per block. (exact r15)
// grid = 256 x 1024 threads. Phase 3: per-wave global_load_lds 4-slab ring,
// prefetch distance 3, counted vmcnt. Epilogue: LDS-staged coalesced stores.
// ---------------------------------------------------------------------------
__global__ __launch_bounds__(1024, 4) void attn_fused(
    const float* __restrict__ qp, const float* __restrict__ kp,
    const unsigned short* __restrict__ vt, const float* __restrict__ wv,
    float* __restrict__ out)
{
    __shared__ __align__(16) unsigned char a_lds[32 * 1024];
    __shared__ __align__(16) unsigned char slab[16 * 4 * 1024];  // 16 waves x 4 x 1KB
    __shared__ float inv_lds[QT];

    const int tid = (int)threadIdx.x;
    const int pid = (int)blockIdx.x;
    const int xcd = pid & 7, slot = pid >> 3;
    const int b   = xcd >> 1;                        // batch 0..3
    const int tnum = slot * 2 + (xcd & 1);           // q-tile 0..63
    const int q0  = tnum * QT;

    float sumwv = 0.f;
    #pragma unroll
    for (int h = 0; h < H; ++h) sumwv += wv[h];
    const float c0s = sumwv * LOG2E;
    const float c1s = 2.0f * LOG2E;

    // ---- phase 1: one k-row per thread, 8 qr-pairs, packed f32 math ----
    {
        const int kk   = tid;
        const int base = (kk >> 5) * 1024 + (kk & 31) * 2;
        float kreg[H];
        const float* krow = kp + (size_t)(b * KDIM + kk) * H;
        #pragma unroll
        for (int i = 0; i < H / 4; ++i) {
            float4 v = *reinterpret_cast<const float4*>(krow + i * 4);
            kreg[i * 4 + 0] = v.x; kreg[i * 4 + 1] = v.y;
            kreg[i * 4 + 2] = v.z; kreg[i * 4 + 3] = v.w;
        }
        const float* eqt = qp + (size_t)((b << 6) | tnum) * 512;

        for (int p = 0; p < 8; ++p) {
            f32x2 s2e = {0.f, 0.f}, s2o = {0.f, 0.f};
            #pragma unroll
            for (int g = 0; g < 8; ++g) {
                const int h = g * 4;
                f32x2 e0 = *reinterpret_cast<const f32x2*>(eqt + (h + 0) * 16 + 2 * p);
                f32x2 e1 = *reinterpret_cast<const f32x2*>(eqt + (h + 1) * 16 + 2 * p);
                f32x2 e2 = *reinterpret_cast<const f32x2*>(eqt + (h + 2) * 16 + 2 * p);
                f32x2 e3 = *reinterpret_cast<const f32x2*>(eqt + (h + 3) * 16 + 2 * p);
                const f32x2 one = {1.f, 1.f};
                f32x2 U0 = e0 * (f32x2){kreg[h + 0], kreg[h + 0]} + one;
                f32x2 U1 = e1 * (f32x2){kreg[h + 1], kreg[h + 1]} + one;
                f32x2 U2 = e2 * (f32x2){kreg[h + 2], kreg[h + 2]} + one;
                f32x2 U3 = e3 * (f32x2){kreg[h + 3], kreg[h + 3]} + one;
                f32x2 n01 = U1 * (f32x2){wv[h + 0], wv[h + 0]}
                          + U0 * (f32x2){wv[h + 1], wv[h + 1]};
                f32x2 n23 = U3 * (f32x2){wv[h + 2], wv[h + 2]}
                          + U2 * (f32x2){wv[h + 3], wv[h + 3]};
                f32x2 d01 = U0 * U1;
                f32x2 d23 = U2 * U3;
                f32x2 n = n01 * d23 + n23 * d01;
                f32x2 d = d01 * d23;
                f32x2 r;
                r.x = __builtin_amdgcn_rcpf(d.x);
                r.y = __builtin_amdgcn_rcpf(d.y);
                if (g & 1) s2o += n * r; else s2e += n * r;
            }
            f32x2 s2 = s2e + s2o;
            float wgtA = __builtin_amdgcn_exp2f(fmaf(-c1s, s2.x, c0s));
            float wgtB = __builtin_amdgcn_exp2f(fmaf(-c1s, s2.y, c0s));
            const int qrA = 2 * p, qrB = 2 * p + 1;
            const int addrA = (base + qrA * 64) ^ ((qrA & 7) << 4);
            const int addrB = (base + qrB * 64) ^ ((qrB & 7) << 4);
            *reinterpret_cast<unsigned short*>(a_lds + addrA) = f32_to_bf16(wgtA);
            *reinterpret_cast<unsigned short*>(a_lds + addrB) = f32_to_bf16(wgtB);
        }
    }
    __syncthreads();

    // ---- phase 2: softmax denominator, one wave per q row ----
    {
        const int row = tid >> 6;                 // 0..15
        const int c   = tid & 63;
        float s = 0.f;
        #pragma unroll
        for (int j = 0; j < 16; ++j) {
            const int k = c + j * 64;
            const int addr = ((k >> 5) * 1024 + row * 64 + (k & 31) * 2)
                             ^ ((row & 7) << 4);
            unsigned int u = *reinterpret_cast<const unsigned short*>(a_lds + addr);
            s += __uint_as_float(u << 16);
        }
        #pragma unroll
        for (int m = 32; m > 0; m >>= 1) s += __shfl_xor(s, m, 64);
        if (c == 0) inv_lds[row] = 1.0f / s;
    }
    __syncthreads();

    // ---- phase 3: MFMA PV, per-wave async V ring (distance 3, 4 slabs) ----
    const int w    = tid >> 6;                    // 0..15
    const int lane = tid & 63;
    const int colb = w * 16;
    const int arow = lane & 15;                   // A row / B col / D col
    const int aq   = lane >> 4;                   // k-quad
    f32x4 acc = {0.f, 0.f, 0.f, 0.f};
    {
        const char* gsrc = reinterpret_cast<const char*>(vt)
                         + ((size_t)(b * 16 + w) * 32) * 1024 + lane * 16;
        char* lbase = reinterpret_cast<char*>(slab) + w * 4096;  // 4 x 1KB ring

        #pragma unroll
        for (int d = 0; d < 3; ++d)
            gll16(gsrc + d * 1024, lbase + d * 1024);

        #pragma unroll 4
        for (int kc = 0; kc < 29; ++kc) {
            gll16(gsrc + (kc + 3) * 1024, lbase + ((kc + 3) & 3) * 1024);
            asm volatile("s_waitcnt vmcnt(3)" ::: "memory");
            const int aaddr = (kc * 1024 + arow * 64 + aq * 16) ^ ((arow & 7) << 4);
            short8 af = *reinterpret_cast<const short8*>(a_lds + aaddr);
            short8 bv = *reinterpret_cast<const short8*>(lbase + (kc & 3) * 1024 + lane * 16);
            acc = __builtin_amdgcn_mfma_f32_16x16x32_bf16(af, bv, acc, 0, 0, 0);
        }
        #define PV_TAIL(KC, VC) { \
            asm volatile("s_waitcnt vmcnt(" #VC ")" ::: "memory"); \
            const int aaddr = ((KC) * 1024 + arow * 64 + aq * 16) ^ ((arow & 7) << 4); \
            short8 af = *reinterpret_cast<const short8*>(a_lds + aaddr); \
            short8 bv = *reinterpret_cast<const short8*>(lbase + ((KC) & 3) * 1024 + lane * 16); \
            acc = __builtin_amdgcn_mfma_f32_16x16x32_bf16(af, bv, acc, 0, 0, 0); }
        PV_TAIL(29, 2)
        PV_TAIL(30, 1)
        PV_TAIL(31, 0)
        #undef PV_TAIL
    }

    // ---- epilogue: stage tile in LDS, then ONE coalesced float4 per thread ----
    __syncthreads();                               // all a_lds MFMA reads done
    {
        float* otile = reinterpret_cast<float*>(a_lds);   // [16][264] padded
        #pragma unroll
        for (int r = 0; r < 4; ++r) {
            const int row = aq * 4 + r;            // C/D: row=(lane>>4)*4+reg
            otile[row * 264 + colb + arow] = acc[r] * inv_lds[row];
        }
    }
    __syncthreads();
    {
        const float* otile = reinterpret_cast<const float*>(a_lds);
        const int row = tid >> 6;                  // 0..15
        const int c4  = (tid & 63) * 4;            // 0..252
        f32x4 v = *reinterpret_cast<const f32x4*>(&otile[row * 264 + c4]);
        *reinterpret_cast<f32x4*>(out + (size_t)(b * QDIM + q0 + row) * VDIM + c4) = v;
    }
}

extern "C" void kernel_launch(void* const* d_in, const int* in_sizes, int n_in,
                              void* d_out, int out_size, void* d_ws, size_t ws_size,
                              hipStream_t stream) {
    const float* queries = (const float*)d_in[0];
    const float* keys    = (const float*)d_in[1];
    const float* values  = (const float*)d_in[2];
    const float* Wq      = (const float*)d_in[3];
    const float* Wk      = (const float*)d_in[4];
    const float* wv      = (const float*)d_in[5];
    float* out = (float*)d_out;

    float* qp = (float*)d_ws;                            // Eq, [256 tiles][32 h][16 r]
    float* kp = qp + (size_t)BATCH * QDIM * H;           // Ek, [4096][32]
    unsigned short* vt  = (unsigned short*)(kp + (size_t)BATCH * KDIM * H); // vt, 2MB
    unsigned short* wtq = vt + (size_t)BATCH * VDIM * KDIM;                 // [32][512]
    unsigned short* wtk = wtq + (size_t)H * EDIM;                           // [32][512]

    hipLaunchKernelGGL(wprep_kernel, dim3(128), dim3(256), 0, stream, Wq, Wk, wtq, wtk);
    hipLaunchKernelGGL(prep_kernel, dim3(512), dim3(256), 0, stream,
                       queries, keys, wtq, wtk, values, qp, kp, vt);
    hipLaunchKernelGGL(attn_fused, dim3(BATCH * (QDIM / QT)), dim3(1024), 0, stream,
                       qp, kp, vt, wv, out);
}

// Round 19
// 31.574 us; speedup vs baseline: 1.5043x; 1.1340x over previous
//
#include <hip/hip_runtime.h>

#define BATCH 4
#define QDIM 1024
#define KDIM 1024
#define EDIM 512
#define H 32
#define VDIM 256
#define QT 16

#define TWO_LOG2E 2.8853900817779268f
#define LOG2E 1.4426950408889634f

typedef __attribute__((ext_vector_type(8))) short short8;
typedef __attribute__((ext_vector_type(4))) float f32x4;
typedef __attribute__((ext_vector_type(2))) float f32x2;

typedef __attribute__((address_space(3))) void lds_void_t;
typedef __attribute__((address_space(1))) const void gbl_cvoid_t;

// async global->LDS, 16B per lane. LDS dest = wave-uniform base + lane*16;
// global src is PER-LANE (pre-swizzle the src to get swizzled LDS layouts).
static __device__ __forceinline__ void gll16(const void* g, void* l) {
    __builtin_amdgcn_global_load_lds((gbl_cvoid_t*)g, (lds_void_t*)l, 16, 0, 0);
}

static __device__ __forceinline__ unsigned short f32_to_bf16(float f) {
    unsigned int bits = __float_as_uint(f);
    return (unsigned short)((bits + 0x7FFFu + ((bits >> 16) & 1u)) >> 16);
}

static __device__ __forceinline__ unsigned int pack_bf16(float a, float b) {
    unsigned int ua = __float_as_uint(a) + 0x8000u;
    unsigned int ub = __float_as_uint(b) + 0x8000u;
    return __builtin_amdgcn_perm(ub, ua, 0x07060302u);  // lo=a.hi16, hi=b.hi16
}

// ---------------------------------------------------------------------------
// Prep kernel, 768 blocks x 256 thr.
// Blocks 0..511: MFMA projection, 16 rows/block, waves = K-quarters.
//   X staged via gll16 with swizzled per-lane src (byte ^ (row&7)<<4) into
//   linear LDS; W transposed inline (vectorized) into swizzled bf16 LDS;
//   fragments consumed from LDS only (global fragment reads = 16-line scatter,
//   r16/r18 lesson). Split-K combine via LDS (r16-verified structure).
// Blocks 512..767: V -> bf16 fragment-major vt[b][w][kc][lane*16B], XCD-affine.
// ---------------------------------------------------------------------------
__global__ __launch_bounds__(256) void prep_kernel(
    const float* __restrict__ qin, const float* __restrict__ kin,
    const float* __restrict__ Wqm, const float* __restrict__ Wkm,
    const float* __restrict__ values,
    float* __restrict__ qp, float* __restrict__ kp,
    unsigned short* __restrict__ vt)
{
    // proj: [0,32K) xs = X[16][2048B] swizzled; [32K,64K) wl = Wt[32][1024B]
    // swizzled; [64K,70K) lacc. vconv: t[64][65] f32 at [0,16.6K).
    __shared__ __align__(16) unsigned char smem[71680];
    const int tid = (int)threadIdx.x;
    const int bid = (int)blockIdx.x;

    if (bid < 512) {
        const int wave = tid >> 6, lane = tid & 63;
        const bool is_k = bid >= 256;
        const float* X = is_k ? kin : qin;
        const float* W = is_k ? Wkm : Wqm;
        float* outp = is_k ? kp : qp;
        const int row0 = (bid & 255) * 16;
        const int arow = lane & 15, aq = lane >> 4;
        const int koff = wave * 128;

        // ---- stage X: 32 half-row DMAs (1KB each), swizzled source ----
        #pragma unroll
        for (int i = 0; i < 8; ++i) {
            const int j = wave * 8 + i;
            const int r = j >> 1, half = j & 1;
            const int swz = (r & 7) << 4;
            const char* src = reinterpret_cast<const char*>(X + (size_t)(row0 + r) * EDIM)
                              + half * 1024 + ((lane * 16) ^ swz);
            char* dst = reinterpret_cast<char*>(smem) + r * 2048 + half * 1024;
            gll16(src, dst);
        }

        // ---- inline W transpose (vectorized): W[e][h] f32 -> wl[h][e] bf16 ----
        {
            #pragma unroll
            for (int i = 0; i < 4; ++i) {
                const int u  = i * 256 + tid;
                const int eq = u >> 3, hg = u & 7;   // e-quad 0..127, h4-group 0..7
                const int e0 = eq * 4, h4 = hg * 4;
                float4 w0 = *reinterpret_cast<const float4*>(W + (size_t)(e0 + 0) * H + h4);
                float4 w1 = *reinterpret_cast<const float4*>(W + (size_t)(e0 + 1) * H + h4);
                float4 w2 = *reinterpret_cast<const float4*>(W + (size_t)(e0 + 2) * H + h4);
                float4 w3 = *reinterpret_cast<const float4*>(W + (size_t)(e0 + 3) * H + h4);
                #define WTROW(HC, C0, C1, C2, C3) { \
                    const int h = h4 + (HC); \
                    const int addr = 32 * 1024 + h * 1024 + ((e0 * 2) ^ ((h & 7) << 4)); \
                    uint2 pk; pk.x = pack_bf16(C0, C1); pk.y = pack_bf16(C2, C3); \
                    *reinterpret_cast<uint2*>(smem + addr) = pk; }
                WTROW(0, w0.x, w1.x, w2.x, w3.x)
                WTROW(1, w0.y, w1.y, w2.y, w3.y)
                WTROW(2, w0.z, w1.z, w2.z, w3.z)
                WTROW(3, w0.w, w1.w, w2.w, w3.w)
                #undef WTROW
            }
        }
        __syncthreads();   // drains gll16 (vmcnt) + ds_writes (lgkmcnt)

        // ---- MFMA: this wave's K-quarter, fragments from swizzled LDS ----
        const int swzr = (arow & 7) << 4;
        f32x4 acc0 = {0.f, 0.f, 0.f, 0.f};
        f32x4 acc1 = {0.f, 0.f, 0.f, 0.f};
        #pragma unroll
        for (int s = 0; s < 4; ++s) {
            const int c = koff + aq * 8 + s * 32;     // float col
            const int A = c * 4;                      // X in-row byte, 32B-aligned
            float4 xa = *reinterpret_cast<const float4*>(smem + arow * 2048 + (A ^ swzr));
            float4 xb = *reinterpret_cast<const float4*>(smem + arow * 2048 + ((A + 16) ^ swzr));
            unsigned int p0 = pack_bf16(xa.x, xa.y);
            unsigned int p1 = pack_bf16(xa.z, xa.w);
            unsigned int p2 = pack_bf16(xb.x, xb.y);
            unsigned int p3 = pack_bf16(xb.z, xb.w);
            uint4 au = make_uint4(p0, p1, p2, p3);
            short8 af = *reinterpret_cast<const short8*>(&au);
            short8 b0 = *reinterpret_cast<const short8*>(
                smem + 32 * 1024 + arow * 1024 + ((c * 2) ^ swzr));
            short8 b1 = *reinterpret_cast<const short8*>(
                smem + 32 * 1024 + (arow + 16) * 1024 + ((c * 2) ^ swzr));
            acc0 = __builtin_amdgcn_mfma_f32_16x16x32_bf16(af, b0, acc0, 0, 0, 0);
            acc1 = __builtin_amdgcn_mfma_f32_16x16x32_bf16(af, b1, acc1, 0, 0, 0);
        }

        // ---- split-K combine via LDS ----
        f32x4* lacc = reinterpret_cast<f32x4*>(smem + 64 * 1024);   // [3][64][2]
        if (wave != 0) {
            lacc[((wave - 1) * 64 + lane) * 2 + 0] = acc0;
            lacc[((wave - 1) * 64 + lane) * 2 + 1] = acc1;
        }
        __syncthreads();
        if (wave == 0) {
            #pragma unroll
            for (int j = 0; j < 3; ++j) {
                acc0 += lacc[(j * 64 + lane) * 2 + 0];
                acc1 += lacc[(j * 64 + lane) * 2 + 1];
            }
            if (is_k) {
                #pragma unroll
                for (int r = 0; r < 4; ++r) {
                    const int row = aq * 4 + r;      // C/D: row=(lane>>4)*4+reg
                    float* orow = outp + (size_t)(row0 + row) * H;
                    orow[arow]      = __builtin_amdgcn_exp2f(acc0[r] * TWO_LOG2E);
                    orow[arow + 16] = __builtin_amdgcn_exp2f(acc1[r] * TWO_LOG2E);
                }
            } else {
                float* tbase = outp + (size_t)(row0 >> 4) * 512;    // [h][16]
                #pragma unroll
                for (int r = 0; r < 4; ++r) {
                    const int row = aq * 4 + r;
                    tbase[arow * 16 + row]        = __builtin_amdgcn_exp2f(acc0[r] * TWO_LOG2E);
                    tbase[(arow + 16) * 16 + row] = __builtin_amdgcn_exp2f(acc1[r] * TWO_LOG2E);
                }
            }
        }
    } else {
        // XCD-affinity decode: pid%8 -> xcd; batch b = xcd>>1. (512 % 8 == 0)
        float* t = reinterpret_cast<float*>(smem);   // [64][65]
        const int pid  = bid - 512;
        const int xcd  = pid & 7, slot = pid >> 3;
        const int b    = xcd >> 1;
        const int tnum = slot * 2 + (xcd & 1);       // 0..63
        const int kt = tnum & 15, ct = tnum >> 4;
        const int k0 = kt * 64, c0 = ct * 64;
        const int col4 = (tid & 15) * 4;
        const int krow = tid >> 4;

        #pragma unroll
        for (int i = 0; i < 4; ++i) {
            const int kk = i * 16 + krow;
            float4 v = *reinterpret_cast<const float4*>(
                values + ((size_t)(b * KDIM + k0 + kk) * VDIM + c0 + col4));
            t[kk * 65 + col4 + 0] = v.x; t[kk * 65 + col4 + 1] = v.y;
            t[kk * 65 + col4 + 2] = v.z; t[kk * 65 + col4 + 3] = v.w;
        }
        __syncthreads();

        const int col = tid >> 2;                    // 0..63 within tile
        const int ks  = (tid & 3) * 16;
        unsigned int pk[8];
        #pragma unroll
        for (int j = 0; j < 8; ++j) {
            unsigned int lo = f32_to_bf16(t[(ks + 2 * j) * 65 + col]);
            unsigned int hi = f32_to_bf16(t[(ks + 2 * j + 1) * 65 + col]);
            pk[j] = lo | (hi << 16);
        }
        // fragment-major store: uint4 idx = ((b*16+w)*32+kc)*64 + aq*16 + arow
        const int colg = c0 + col;
        const int w_ = colg >> 4, arow_ = colg & 15;
        const int kA = k0 + ks, kB = kA + 8;
        uint4* vt4 = reinterpret_cast<uint4*>(vt);
        const size_t idxA = ((size_t)(b * 16 + w_) * 32 + (kA >> 5)) * 64
                            + ((kA >> 3) & 3) * 16 + arow_;
        const size_t idxB = ((size_t)(b * 16 + w_) * 32 + (kB >> 5)) * 64
                            + ((kB >> 3) & 3) * 16 + arow_;
        vt4[idxA] = make_uint4(pk[0], pk[1], pk[2], pk[3]);
        vt4[idxB] = make_uint4(pk[4], pk[5], pk[6], pk[7]);
    }
}

// ---------------------------------------------------------------------------
// Fused scores -> softmax -> MFMA PV. QT=16 q rows per block. (exact r15)
// grid = 256 x 1024 threads. Phase 3: per-wave global_load_lds 4-slab ring,
// prefetch distance 3, counted vmcnt. Epilogue: LDS-staged coalesced stores.
// ---------------------------------------------------------------------------
__global__ __launch_bounds__(1024, 4) void attn_fused(
    const float* __restrict__ qp, const float* __restrict__ kp,
    const unsigned short* __restrict__ vt, const float* __restrict__ wv,
    float* __restrict__ out)
{
    __shared__ __align__(16) unsigned char a_lds[32 * 1024];
    __shared__ __align__(16) unsigned char slab[16 * 4 * 1024];  // 16 waves x 4 x 1KB
    __shared__ float inv_lds[QT];

    const int tid = (int)threadIdx.x;
    const int pid = (int)blockIdx.x;
    const int xcd = pid & 7, slot = pid >> 3;
    const int b   = xcd >> 1;                        // batch 0..3
    const int tnum = slot * 2 + (xcd & 1);           // q-tile 0..63
    const int q0  = tnum * QT;

    float sumwv = 0.f;
    #pragma unroll
    for (int h = 0; h < H; ++h) sumwv += wv[h];
    const float c0s = sumwv * LOG2E;
    const float c1s = 2.0f * LOG2E;

    // ---- phase 1: one k-row per thread, 8 qr-pairs, packed f32 math ----
    {
        const int kk   = tid;
        const int base = (kk >> 5) * 1024 + (kk & 31) * 2;
        float kreg[H];
        const float* krow = kp + (size_t)(b * KDIM + kk) * H;
        #pragma unroll
        for (int i = 0; i < H / 4; ++i) {
            float4 v = *reinterpret_cast<const float4*>(krow + i * 4);
            kreg[i * 4 + 0] = v.x; kreg[i * 4 + 1] = v.y;
            kreg[i * 4 + 2] = v.z; kreg[i * 4 + 3] = v.w;
        }
        const float* eqt = qp + (size_t)((b << 6) | tnum) * 512;

        for (int p = 0; p < 8; ++p) {
            f32x2 s2e = {0.f, 0.f}, s2o = {0.f, 0.f};
            #pragma unroll
            for (int g = 0; g < 8; ++g) {
                const int h = g * 4;
                f32x2 e0 = *reinterpret_cast<const f32x2*>(eqt + (h + 0) * 16 + 2 * p);
                f32x2 e1 = *reinterpret_cast<const f32x2*>(eqt + (h + 1) * 16 + 2 * p);
                f32x2 e2 = *reinterpret_cast<const f32x2*>(eqt + (h + 2) * 16 + 2 * p);
                f32x2 e3 = *reinterpret_cast<const f32x2*>(eqt + (h + 3) * 16 + 2 * p);
                const f32x2 one = {1.f, 1.f};
                f32x2 U0 = e0 * (f32x2){kreg[h + 0], kreg[h + 0]} + one;
                f32x2 U1 = e1 * (f32x2){kreg[h + 1], kreg[h + 1]} + one;
                f32x2 U2 = e2 * (f32x2){kreg[h + 2], kreg[h + 2]} + one;
                f32x2 U3 = e3 * (f32x2){kreg[h + 3], kreg[h + 3]} + one;
                f32x2 n01 = U1 * (f32x2){wv[h + 0], wv[h + 0]}
                          + U0 * (f32x2){wv[h + 1], wv[h + 1]};
                f32x2 n23 = U3 * (f32x2){wv[h + 2], wv[h + 2]}
                          + U2 * (f32x2){wv[h + 3], wv[h + 3]};
                f32x2 d01 = U0 * U1;
                f32x2 d23 = U2 * U3;
                f32x2 n = n01 * d23 + n23 * d01;
                f32x2 d = d01 * d23;
                f32x2 r;
                r.x = __builtin_amdgcn_rcpf(d.x);
                r.y = __builtin_amdgcn_rcpf(d.y);
                if (g & 1) s2o += n * r; else s2e += n * r;
            }
            f32x2 s2 = s2e + s2o;
            float wgtA = __builtin_amdgcn_exp2f(fmaf(-c1s, s2.x, c0s));
            float wgtB = __builtin_amdgcn_exp2f(fmaf(-c1s, s2.y, c0s));
            const int qrA = 2 * p, qrB = 2 * p + 1;
            const int addrA = (base + qrA * 64) ^ ((qrA & 7) << 4);
            const int addrB = (base + qrB * 64) ^ ((qrB & 7) << 4);
            *reinterpret_cast<unsigned short*>(a_lds + addrA) = f32_to_bf16(wgtA);
            *reinterpret_cast<unsigned short*>(a_lds + addrB) = f32_to_bf16(wgtB);
        }
    }
    __syncthreads();

    // ---- phase 2: softmax denominator, one wave per q row ----
    {
        const int row = tid >> 6;                 // 0..15
        const int c   = tid & 63;
        float s = 0.f;
        #pragma unroll
        for (int j = 0; j < 16; ++j) {
            const int k = c + j * 64;
            const int addr = ((k >> 5) * 1024 + row * 64 + (k & 31) * 2)
                             ^ ((row & 7) << 4);
            unsigned int u = *reinterpret_cast<const unsigned short*>(a_lds + addr);
            s += __uint_as_float(u << 16);
        }
        #pragma unroll
        for (int m = 32; m > 0; m >>= 1) s += __shfl_xor(s, m, 64);
        if (c == 0) inv_lds[row] = 1.0f / s;
    }
    __syncthreads();

    // ---- phase 3: MFMA PV, per-wave async V ring (distance 3, 4 slabs) ----
    const int w    = tid >> 6;                    // 0..15
    const int lane = tid & 63;
    const int colb = w * 16;
    const int arow = lane & 15;                   // A row / B col / D col
    const int aq   = lane >> 4;                   // k-quad
    f32x4 acc = {0.f, 0.f, 0.f, 0.f};
    {
        const char* gsrc = reinterpret_cast<const char*>(vt)
                         + ((size_t)(b * 16 + w) * 32) * 1024 + lane * 16;
        char* lbase = reinterpret_cast<char*>(slab) + w * 4096;  // 4 x 1KB ring

        #pragma unroll
        for (int d = 0; d < 3; ++d)
            gll16(gsrc + d * 1024, lbase + d * 1024);

        #pragma unroll 4
        for (int kc = 0; kc < 29; ++kc) {
            gll16(gsrc + (kc + 3) * 1024, lbase + ((kc + 3) & 3) * 1024);
            asm volatile("s_waitcnt vmcnt(3)" ::: "memory");
            const int aaddr = (kc * 1024 + arow * 64 + aq * 16) ^ ((arow & 7) << 4);
            short8 af = *reinterpret_cast<const short8*>(a_lds + aaddr);
            short8 bv = *reinterpret_cast<const short8*>(lbase + (kc & 3) * 1024 + lane * 16);
            acc = __builtin_amdgcn_mfma_f32_16x16x32_bf16(af, bv, acc, 0, 0, 0);
        }
        #define PV_TAIL(KC, VC) { \
            asm volatile("s_waitcnt vmcnt(" #VC ")" ::: "memory"); \
            const int aaddr = ((KC) * 1024 + arow * 64 + aq * 16) ^ ((arow & 7) << 4); \
            short8 af = *reinterpret_cast<const short8*>(a_lds + aaddr); \
            short8 bv = *reinterpret_cast<const short8*>(lbase + ((KC) & 3) * 1024 + lane * 16); \
            acc = __builtin_amdgcn_mfma_f32_16x16x32_bf16(af, bv, acc, 0, 0, 0); }
        PV_TAIL(29, 2)
        PV_TAIL(30, 1)
        PV_TAIL(31, 0)
        #undef PV_TAIL
    }

    // ---- epilogue: stage tile in LDS, then ONE coalesced float4 per thread ----
    __syncthreads();                               // all a_lds MFMA reads done
    {
        float* otile = reinterpret_cast<float*>(a_lds);   // [16][264] padded
        #pragma unroll
        for (int r = 0; r < 4; ++r) {
            const int row = aq * 4 + r;            // C/D: row=(lane>>4)*4+reg
            otile[row * 264 + colb + arow] = acc[r] * inv_lds[row];
        }
    }
    __syncthreads();
    {
        const float* otile = reinterpret_cast<const float*>(a_lds);
        const int row = tid >> 6;                  // 0..15
        const int c4  = (tid & 63) * 4;            // 0..252
        f32x4 v = *reinterpret_cast<const f32x4*>(&otile[row * 264 + c4]);
        *reinterpret_cast<f32x4*>(out + (size_t)(b * QDIM + q0 + row) * VDIM + c4) = v;
    }
}

extern "C" void kernel_launch(void* const* d_in, const int* in_sizes, int n_in,
                              void* d_out, int out_size, void* d_ws, size_t ws_size,
                              hipStream_t stream) {
    const float* queries = (const float*)d_in[0];
    const float* keys    = (const float*)d_in[1];
    const float* values  = (const float*)d_in[2];
    const float* Wq      = (const float*)d_in[3];
    const float* Wk      = (const float*)d_in[4];
    const float* wv      = (const float*)d_in[5];
    float* out = (float*)d_out;

    float* qp = (float*)d_ws;                            // Eq, [256 tiles][32 h][16 r]
    float* kp = qp + (size_t)BATCH * QDIM * H;           // Ek, [4096][32]
    unsigned short* vt = (unsigned short*)(kp + (size_t)BATCH * KDIM * H); // vt, 2MB

    hipLaunchKernelGGL(prep_kernel, dim3(768), dim3(256), 0, stream,
                       queries, keys, Wq, Wk, values, qp, kp, vt);
    hipLaunchKernelGGL(attn_fused, dim3(BATCH * (QDIM / QT)), dim3(1024), 0, stream,
                       qp, kp, vt, wv, out);
}

// Round 21
// 31.558 us; speedup vs baseline: 1.5051x; 1.0005x over previous
//
#include <hip/hip_runtime.h>

#define BATCH 4
#define QDIM 1024
#define KDIM 1024
#define EDIM 512
#define H 32
#define VDIM 256
#define QT 16

#define TWO_LOG2E 2.8853900817779268f
#define LOG2E 1.4426950408889634f

typedef __attribute__((ext_vector_type(8))) short short8;
typedef __attribute__((ext_vector_type(4))) float f32x4;
typedef __attribute__((ext_vector_type(2))) float f32x2;

typedef __attribute__((address_space(3))) void lds_void_t;
typedef __attribute__((address_space(1))) const void gbl_cvoid_t;

// async global->LDS, 16B per lane. LDS dest = wave-uniform base + lane*16;
// global src is PER-LANE (pre-swizzle the src to get swizzled LDS layouts).
static __device__ __forceinline__ void gll16(const void* g, void* l) {
    __builtin_amdgcn_global_load_lds((gbl_cvoid_t*)g, (lds_void_t*)l, 16, 0, 0);
}

static __device__ __forceinline__ unsigned short f32_to_bf16(float f) {
    unsigned int bits = __float_as_uint(f);
    return (unsigned short)((bits + 0x7FFFu + ((bits >> 16) & 1u)) >> 16);
}

static __device__ __forceinline__ unsigned int pack_bf16(float a, float b) {
    unsigned int ua = __float_as_uint(a) + 0x8000u;
    unsigned int ub = __float_as_uint(b) + 0x8000u;
    return __builtin_amdgcn_perm(ub, ua, 0x07060302u);  // lo=a.hi16, hi=b.hi16
}

// ---------------------------------------------------------------------------
// Prep kernel, 768 blocks x 256 thr.
// Blocks 0..511: MFMA projection, 16 rows/block, waves = K-quarters.
//   X staged via gll16 with swizzled per-lane src (byte ^ (row&7)<<4) into
//   linear LDS; W transposed inline (vectorized) into swizzled bf16 LDS;
//   fragments consumed from LDS only (global fragment reads = 16-line scatter,
//   r16/r18 lesson). Split-K combine via LDS (r16-verified structure).
// Blocks 512..767: V -> bf16 fragment-major vt[b][w][kc][lane*16B], XCD-affine.
// ---------------------------------------------------------------------------
__global__ __launch_bounds__(256) void prep_kernel(
    const float* __restrict__ qin, const float* __restrict__ kin,
    const float* __restrict__ Wqm, const float* __restrict__ Wkm,
    const float* __restrict__ values,
    float* __restrict__ qp, float* __restrict__ kp,
    unsigned short* __restrict__ vt)
{
    // proj: [0,32K) xs = X[16][2048B] swizzled; [32K,64K) wl = Wt[32][1024B]
    // swizzled; [64K,70K) lacc. vconv: t[64][65] f32 at [0,16.6K).
    __shared__ __align__(16) unsigned char smem[71680];
    const int tid = (int)threadIdx.x;
    const int bid = (int)blockIdx.x;

    if (bid < 512) {
        const int wave = tid >> 6, lane = tid & 63;
        const bool is_k = bid >= 256;
        const float* X = is_k ? kin : qin;
        const float* W = is_k ? Wkm : Wqm;
        float* outp = is_k ? kp : qp;
        const int row0 = (bid & 255) * 16;
        const int arow = lane & 15, aq = lane >> 4;
        const int koff = wave * 128;

        // ---- stage X: 32 half-row DMAs (1KB each), swizzled source ----
        #pragma unroll
        for (int i = 0; i < 8; ++i) {
            const int j = wave * 8 + i;
            const int r = j >> 1, half = j & 1;
            const int swz = (r & 7) << 4;
            const char* src = reinterpret_cast<const char*>(X + (size_t)(row0 + r) * EDIM)
                              + half * 1024 + ((lane * 16) ^ swz);
            char* dst = reinterpret_cast<char*>(smem) + r * 2048 + half * 1024;
            gll16(src, dst);
        }

        // ---- inline W transpose (vectorized): W[e][h] f32 -> wl[h][e] bf16 ----
        {
            #pragma unroll
            for (int i = 0; i < 4; ++i) {
                const int u  = i * 256 + tid;
                const int eq = u >> 3, hg = u & 7;   // e-quad 0..127, h4-group 0..7
                const int e0 = eq * 4, h4 = hg * 4;
                float4 w0 = *reinterpret_cast<const float4*>(W + (size_t)(e0 + 0) * H + h4);
                float4 w1 = *reinterpret_cast<const float4*>(W + (size_t)(e0 + 1) * H + h4);
                float4 w2 = *reinterpret_cast<const float4*>(W + (size_t)(e0 + 2) * H + h4);
                float4 w3 = *reinterpret_cast<const float4*>(W + (size_t)(e0 + 3) * H + h4);
                #define WTROW(HC, C0, C1, C2, C3) { \
                    const int h = h4 + (HC); \
                    const int addr = 32 * 1024 + h * 1024 + ((e0 * 2) ^ ((h & 7) << 4)); \
                    uint2 pk; pk.x = pack_bf16(C0, C1); pk.y = pack_bf16(C2, C3); \
                    *reinterpret_cast<uint2*>(smem + addr) = pk; }
                WTROW(0, w0.x, w1.x, w2.x, w3.x)
                WTROW(1, w0.y, w1.y, w2.y, w3.y)
                WTROW(2, w0.z, w1.z, w2.z, w3.z)
                WTROW(3, w0.w, w1.w, w2.w, w3.w)
                #undef WTROW
            }
        }
        __syncthreads();   // drains gll16 (vmcnt) + ds_writes (lgkmcnt)

        // ---- MFMA: this wave's K-quarter, fragments from swizzled LDS ----
        const int swzr = (arow & 7) << 4;
        f32x4 acc0 = {0.f, 0.f, 0.f, 0.f};
        f32x4 acc1 = {0.f, 0.f, 0.f, 0.f};
        #pragma unroll
        for (int s = 0; s < 4; ++s) {
            const int c = koff + aq * 8 + s * 32;     // float col
            const int A = c * 4;                      // X in-row byte, 32B-aligned
            float4 xa = *reinterpret_cast<const float4*>(smem + arow * 2048 + (A ^ swzr));
            float4 xb = *reinterpret_cast<const float4*>(smem + arow * 2048 + ((A + 16) ^ swzr));
            unsigned int p0 = pack_bf16(xa.x, xa.y);
            unsigned int p1 = pack_bf16(xa.z, xa.w);
            unsigned int p2 = pack_bf16(xb.x, xb.y);
            unsigned int p3 = pack_bf16(xb.z, xb.w);
            uint4 au = make_uint4(p0, p1, p2, p3);
            short8 af = *reinterpret_cast<const short8*>(&au);
            short8 b0 = *reinterpret_cast<const short8*>(
                smem + 32 * 1024 + arow * 1024 + ((c * 2) ^ swzr));
            short8 b1 = *reinterpret_cast<const short8*>(
                smem + 32 * 1024 + (arow + 16) * 1024 + ((c * 2) ^ swzr));
            acc0 = __builtin_amdgcn_mfma_f32_16x16x32_bf16(af, b0, acc0, 0, 0, 0);
            acc1 = __builtin_amdgcn_mfma_f32_16x16x32_bf16(af, b1, acc1, 0, 0, 0);
        }

        // ---- split-K combine via LDS ----
        f32x4* lacc = reinterpret_cast<f32x4*>(smem + 64 * 1024);   // [3][64][2]
        if (wave != 0) {
            lacc[((wave - 1) * 64 + lane) * 2 + 0] = acc0;
            lacc[((wave - 1) * 64 + lane) * 2 + 1] = acc1;
        }
        __syncthreads();
        if (wave == 0) {
            #pragma unroll
            for (int j = 0; j < 3; ++j) {
                acc0 += lacc[(j * 64 + lane) * 2 + 0];
                acc1 += lacc[(j * 64 + lane) * 2 + 1];
            }
            if (is_k) {
                #pragma unroll
                for (int r = 0; r < 4; ++r) {
                    const int row = aq * 4 + r;      // C/D: row=(lane>>4)*4+reg
                    float* orow = outp + (size_t)(row0 + row) * H;
                    orow[arow]      = __builtin_amdgcn_exp2f(acc0[r] * TWO_LOG2E);
                    orow[arow + 16] = __builtin_amdgcn_exp2f(acc1[r] * TWO_LOG2E);
                }
            } else {
                float* tbase = outp + (size_t)(row0 >> 4) * 512;    // [h][16]
                #pragma unroll
                for (int r = 0; r < 4; ++r) {
                    const int row = aq * 4 + r;
                    tbase[arow * 16 + row]        = __builtin_amdgcn_exp2f(acc0[r] * TWO_LOG2E);
                    tbase[(arow + 16) * 16 + row] = __builtin_amdgcn_exp2f(acc1[r] * TWO_LOG2E);
                }
            }
        }
    } else {
        // XCD-affinity decode: pid%8 -> xcd; batch b = xcd>>1. (512 % 8 == 0)
        float* t = reinterpret_cast<float*>(smem);   // [64][65]
        const int pid  = bid - 512;
        const int xcd  = pid & 7, slot = pid >> 3;
        const int b    = xcd >> 1;
        const int tnum = slot * 2 + (xcd & 1);       // 0..63
        const int kt = tnum & 15, ct = tnum >> 4;
        const int k0 = kt * 64, c0 = ct * 64;
        const int col4 = (tid & 15) * 4;
        const int krow = tid >> 4;

        #pragma unroll
        for (int i = 0; i < 4; ++i) {
            const int kk = i * 16 + krow;
            float4 v = *reinterpret_cast<const float4*>(
                values + ((size_t)(b * KDIM + k0 + kk) * VDIM + c0 + col4));
            t[kk * 65 + col4 + 0] = v.x; t[kk * 65 + col4 + 1] = v.y;
            t[kk * 65 + col4 + 2] = v.z; t[kk * 65 + col4 + 3] = v.w;
        }
        __syncthreads();

        const int col = tid >> 2;                    // 0..63 within tile
        const int ks  = (tid & 3) * 16;
        unsigned int pk[8];
        #pragma unroll
        for (int j = 0; j < 8; ++j) {
            unsigned int lo = f32_to_bf16(t[(ks + 2 * j) * 65 + col]);
            unsigned int hi = f32_to_bf16(t[(ks + 2 * j + 1) * 65 + col]);
            pk[j] = lo | (hi << 16);
        }
        // fragment-major store: uint4 idx = ((b*16+w)*32+kc)*64 + aq*16 + arow
        const int colg = c0 + col;
        const int w_ = colg >> 4, arow_ = colg & 15;
        const int kA = k0 + ks, kB = kA + 8;
        uint4* vt4 = reinterpret_cast<uint4*>(vt);
        const size_t idxA = ((size_t)(b * 16 + w_) * 32 + (kA >> 5)) * 64
                            + ((kA >> 3) & 3) * 16 + arow_;
        const size_t idxB = ((size_t)(b * 16 + w_) * 32 + (kB >> 5)) * 64
                            + ((kB >> 3) & 3) * 16 + arow_;
        vt4[idxA] = make_uint4(pk[0], pk[1], pk[2], pk[3]);
        vt4[idxB] = make_uint4(pk[4], pk[5], pk[6], pk[7]);
    }
}

// ---------------------------------------------------------------------------
// Fused scores -> softmax -> MFMA PV. QT=16 q rows per block. (exact r15)
// grid = 256 x 1024 threads. Phase 3: per-wave global_load_lds 4-slab ring,
// prefetch distance 3, counted vmcnt. Epilogue: LDS-staged coalesced stores.
// ---------------------------------------------------------------------------
__global__ __launch_bounds__(1024, 4) void attn_fused(
    const float* __restrict__ qp, const float* __restrict__ kp,
    const unsigned short* __restrict__ vt, const float* __restrict__ wv,
    float* __restrict__ out)
{
    __shared__ __align__(16) unsigned char a_lds[32 * 1024];
    __shared__ __align__(16) unsigned char slab[16 * 4 * 1024];  // 16 waves x 4 x 1KB
    __shared__ float inv_lds[QT];

    const int tid = (int)threadIdx.x;
    const int pid = (int)blockIdx.x;
    const int xcd = pid & 7, slot = pid >> 3;
    const int b   = xcd >> 1;                        // batch 0..3
    const int tnum = slot * 2 + (xcd & 1);           // q-tile 0..63
    const int q0  = tnum * QT;

    float sumwv = 0.f;
    #pragma unroll
    for (int h = 0; h < H; ++h) sumwv += wv[h];
    const float c0s = sumwv * LOG2E;
    const float c1s = 2.0f * LOG2E;

    // ---- phase 1: one k-row per thread, 8 qr-pairs, packed f32 math ----
    {
        const int kk   = tid;
        const int base = (kk >> 5) * 1024 + (kk & 31) * 2;
        float kreg[H];
        const float* krow = kp + (size_t)(b * KDIM + kk) * H;
        #pragma unroll
        for (int i = 0; i < H / 4; ++i) {
            float4 v = *reinterpret_cast<const float4*>(krow + i * 4);
            kreg[i * 4 + 0] = v.x; kreg[i * 4 + 1] = v.y;
            kreg[i * 4 + 2] = v.z; kreg[i * 4 + 3] = v.w;
        }
        const float* eqt = qp + (size_t)((b << 6) | tnum) * 512;

        for (int p = 0; p < 8; ++p) {
            f32x2 s2e = {0.f, 0.f}, s2o = {0.f, 0.f};
            #pragma unroll
            for (int g = 0; g < 8; ++g) {
                const int h = g * 4;
                f32x2 e0 = *reinterpret_cast<const f32x2*>(eqt + (h + 0) * 16 + 2 * p);
                f32x2 e1 = *reinterpret_cast<const f32x2*>(eqt + (h + 1) * 16 + 2 * p);
                f32x2 e2 = *reinterpret_cast<const f32x2*>(eqt + (h + 2) * 16 + 2 * p);
                f32x2 e3 = *reinterpret_cast<const f32x2*>(eqt + (h + 3) * 16 + 2 * p);
                const f32x2 one = {1.f, 1.f};
                f32x2 U0 = e0 * (f32x2){kreg[h + 0], kreg[h + 0]} + one;
                f32x2 U1 = e1 * (f32x2){kreg[h + 1], kreg[h + 1]} + one;
                f32x2 U2 = e2 * (f32x2){kreg[h + 2], kreg[h + 2]} + one;
                f32x2 U3 = e3 * (f32x2){kreg[h + 3], kreg[h + 3]} + one;
                f32x2 n01 = U1 * (f32x2){wv[h + 0], wv[h + 0]}
                          + U0 * (f32x2){wv[h + 1], wv[h + 1]};
                f32x2 n23 = U3 * (f32x2){wv[h + 2], wv[h + 2]}
                          + U2 * (f32x2){wv[h + 3], wv[h + 3]};
                f32x2 d01 = U0 * U1;
                f32x2 d23 = U2 * U3;
                f32x2 n = n01 * d23 + n23 * d01;
                f32x2 d = d01 * d23;
                f32x2 r;
                r.x = __builtin_amdgcn_rcpf(d.x);
                r.y = __builtin_amdgcn_rcpf(d.y);
                if (g & 1) s2o += n * r; else s2e += n * r;
            }
            f32x2 s2 = s2e + s2o;
            float wgtA = __builtin_amdgcn_exp2f(fmaf(-c1s, s2.x, c0s));
            float wgtB = __builtin_amdgcn_exp2f(fmaf(-c1s, s2.y, c0s));
            const int qrA = 2 * p, qrB = 2 * p + 1;
            const int addrA = (base + qrA * 64) ^ ((qrA & 7) << 4);
            const int addrB = (base + qrB * 64) ^ ((qrB & 7) << 4);
            *reinterpret_cast<unsigned short*>(a_lds + addrA) = f32_to_bf16(wgtA);
            *reinterpret_cast<unsigned short*>(a_lds + addrB) = f32_to_bf16(wgtB);
        }
    }
    __syncthreads();

    // ---- phase 2: softmax denominator, one wave per q row ----
    {
        const int row = tid >> 6;                 // 0..15
        const int c   = tid & 63;
        float s = 0.f;
        #pragma unroll
        for (int j = 0; j < 16; ++j) {
            const int k = c + j * 64;
            const int addr = ((k >> 5) * 1024 + row * 64 + (k & 31) * 2)
                             ^ ((row & 7) << 4);
            unsigned int u = *reinterpret_cast<const unsigned short*>(a_lds + addr);
            s += __uint_as_float(u << 16);
        }
        #pragma unroll
        for (int m = 32; m > 0; m >>= 1) s += __shfl_xor(s, m, 64);
        if (c == 0) inv_lds[row] = 1.0f / s;
    }
    __syncthreads();

    // ---- phase 3: MFMA PV, per-wave async V ring (distance 3, 4 slabs) ----
    const int w    = tid >> 6;                    // 0..15
    const int lane = tid & 63;
    const int colb = w * 16;
    const int arow = lane & 15;                   // A row / B col / D col
    const int aq   = lane >> 4;                   // k-quad
    f32x4 acc = {0.f, 0.f, 0.f, 0.f};
    {
        const char* gsrc = reinterpret_cast<const char*>(vt)
                         + ((size_t)(b * 16 + w) * 32) * 1024 + lane * 16;
        char* lbase = reinterpret_cast<char*>(slab) + w * 4096;  // 4 x 1KB ring

        #pragma unroll
        for (int d = 0; d < 3; ++d)
            gll16(gsrc + d * 1024, lbase + d * 1024);

        #pragma unroll 4
        for (int kc = 0; kc < 29; ++kc) {
            gll16(gsrc + (kc + 3) * 1024, lbase + ((kc + 3) & 3) * 1024);
            asm volatile("s_waitcnt vmcnt(3)" ::: "memory");
            const int aaddr = (kc * 1024 + arow * 64 + aq * 16) ^ ((arow & 7) << 4);
            short8 af = *reinterpret_cast<const short8*>(a_lds + aaddr);
            short8 bv = *reinterpret_cast<const short8*>(lbase + (kc & 3) * 1024 + lane * 16);
            acc = __builtin_amdgcn_mfma_f32_16x16x32_bf16(af, bv, acc, 0, 0, 0);
        }
        #define PV_TAIL(KC, VC) { \
            asm volatile("s_waitcnt vmcnt(" #VC ")" ::: "memory"); \
            const int aaddr = ((KC) * 1024 + arow * 64 + aq * 16) ^ ((arow & 7) << 4); \
            short8 af = *reinterpret_cast<const short8*>(a_lds + aaddr); \
            short8 bv = *reinterpret_cast<const short8*>(lbase + ((KC) & 3) * 1024 + lane * 16); \
            acc = __builtin_amdgcn_mfma_f32_16x16x32_bf16(af, bv, acc, 0, 0, 0); }
        PV_TAIL(29, 2)
        PV_TAIL(30, 1)
        PV_TAIL(31, 0)
        #undef PV_TAIL
    }

    // ---- epilogue: stage tile in LDS, then ONE coalesced float4 per thread ----
    __syncthreads();                               // all a_lds MFMA reads done
    {
        float* otile = reinterpret_cast<float*>(a_lds);   // [16][264] padded
        #pragma unroll
        for (int r = 0; r < 4; ++r) {
            const int row = aq * 4 + r;            // C/D: row=(lane>>4)*4+reg
            otile[row * 264 + colb + arow] = acc[r] * inv_lds[row];
        }
    }
    __syncthreads();
    {
        const float* otile = reinterpret_cast<const float*>(a_lds);
        const int row = tid >> 6;                  // 0..15
        const int c4  = (tid & 63) * 4;            // 0..252
        f32x4 v = *reinterpret_cast<const f32x4*>(&otile[row * 264 + c4]);
        *reinterpret_cast<f32x4*>(out + (size_t)(b * QDIM + q0 + row) * VDIM + c4) = v;
    }
}

extern "C" void kernel_launch(void* const* d_in, const int* in_sizes, int n_in,
                              void* d_out, int out_size, void* d_ws, size_t ws_size,
                              hipStream_t stream) {
    const float* queries = (const float*)d_in[0];
    const float* keys    = (const float*)d_in[1];
    const float* values  = (const float*)d_in[2];
    const float* Wq      = (const float*)d_in[3];
    const float* Wk      = (const float*)d_in[4];
    const float* wv      = (const float*)d_in[5];
    float* out = (float*)d_out;

    float* qp = (float*)d_ws;                            // Eq, [256 tiles][32 h][16 r]
    float* kp = qp + (size_t)BATCH * QDIM * H;           // Ek, [4096][32]
    unsigned short* vt = (unsigned short*)(kp + (size_t)BATCH * KDIM * H); // vt, 2MB

    hipLaunchKernelGGL(prep_kernel, dim3(768), dim3(256), 0, stream,
                       queries, keys, Wq, Wk, values, qp, kp, vt);
    hipLaunchKernelGGL(attn_fused, dim3(BATCH * (QDIM / QT)), dim3(1024), 0, stream,
                       qp, kp, vt, wv, out);
}